// Round 2
// baseline (1589.940 us; speedup 1.0000x reference)
//
#include <hip/hip_runtime.h>

#define N_NODES 100000
#define N_EDGES 1600000
#define N_SUP 2
#define IN_DIM 256
#define OUT_DIM 64
#define N_TOT_EDGES (N_SUP * N_EDGES)   // 3,200,000
#define GM 64                           // GEMM M-tile per block
#define NBLK ((N_NODES + GM - 1) / GM)  // 1563

#define SHIFT 8                         // 256 nodes per bucket (LDS acc tile)
#define BUCKN 256
#define NBUCK ((N_NODES + BUCKN - 1) / BUCKN)      // 391
#define CAP 9216                        // staging capacity/bucket: mean 8184, sigma~90
#define CHUNK 4096                      // edges per bin block
#define BGRID ((N_TOT_EDGES + CHUNK - 1) / CHUNK)  // 782

typedef __attribute__((ext_vector_type(8))) short short8;   // 8 bf16
typedef __attribute__((ext_vector_type(4))) float floatx4;  // MFMA acc
typedef unsigned long long u64;

__device__ inline ushort f2bf(float f) {          // fp32 -> bf16 RNE
    unsigned u = __float_as_uint(f);
    return (ushort)((u + 0x7fffu + ((u >> 16) & 1u)) >> 16);
}
__device__ inline float bf2f(ushort h) {
    return __uint_as_float(((unsigned)h) << 16);
}

// Native LDS fp32 atomic add. HIP's atomicAdd(float*) on LDS lowers to a CAS
// loop (safe-fp-atomics default, ~250 cyc serial per op -- the R1 regression).
// ds_add_f32 is the hardware op; addr = low 32 bits of the generic LDS pointer.
__device__ inline void lds_fadd(float* p, float v) {
    asm volatile("ds_add_f32 %0, %1"
                 :: "v"((unsigned)(size_t)p), "v"(v) : "memory");
}

// ---------------------------------------------------------------------------
// W pre-swizzle into mfma_f32_16x16x32_bf16 B-fragment order (unchanged) +
// bucket-cursor init folded in.
// ---------------------------------------------------------------------------
__global__ __launch_bounds__(256) void wb_kernel(
    const float* __restrict__ W, ushort* __restrict__ Wb,
    int* __restrict__ bcur)
{
    int idx = blockIdx.x * 256 + threadIdx.x;      // 0..32767
    if (idx < NBUCK) bcur[idx] = idx * CAP;
    int j    = idx & 7;
    int lane = (idx >> 3) & 63;
    int nt   = (idx >> 9) & 7;
    int ks   = idx >> 12;
    int k = ks * 32 + (lane >> 4) * 8 + j;
    int n = nt * 16 + (lane & 15);
    Wb[idx] = f2bf(W[((size_t)(n >> 6) * IN_DIM + k) * OUT_DIM + (n & 63)]);
}

// ---------------------------------------------------------------------------
// MFMA GEMM (unchanged): psb[sup][node][64] bf16 = x @ W[sup]
// ---------------------------------------------------------------------------
__global__ __launch_bounds__(256) void gemm_kernel(
    const float* __restrict__ x, const ushort* __restrict__ Wb,
    ushort* __restrict__ psb)
{
    __shared__ __align__(16) ushort xs[GM][264];
    const int row0 = blockIdx.x * GM;
    const int trow = threadIdx.x >> 6;
    const int tcol = threadIdx.x & 63;

#pragma unroll
    for (int j = 0; j < 16; ++j) {
        int r = j * 4 + trow;
        int gr = row0 + r;
        if (gr > N_NODES - 1) gr = N_NODES - 1;
        float4 v = ((const float4*)x)[(size_t)gr * 64 + tcol];
        ushort4 h;
        h.x = f2bf(v.x); h.y = f2bf(v.y); h.z = f2bf(v.z); h.w = f2bf(v.w);
        *(ushort4*)&xs[r][tcol * 4] = h;
    }
    __syncthreads();

    const int wave = threadIdx.x >> 6;
    const int lane = threadIdx.x & 63;
    const int q = lane >> 4;
    const int m = lane & 15;
    const int nt0 = wave * 2;

    floatx4 acc[4][2];
#pragma unroll
    for (int mt = 0; mt < 4; ++mt)
#pragma unroll
        for (int nt = 0; nt < 2; ++nt)
            acc[mt][nt] = (floatx4){0.f, 0.f, 0.f, 0.f};

    const short8* Wbv = (const short8*)Wb;
#pragma unroll
    for (int ks = 0; ks < 8; ++ks) {
        short8 b0 = Wbv[((ks * 8) + nt0) * 64 + lane];
        short8 b1 = Wbv[((ks * 8) + nt0 + 1) * 64 + lane];
#pragma unroll
        for (int mt = 0; mt < 4; ++mt) {
            short8 a = *(const short8*)&xs[mt * 16 + m][ks * 32 + q * 8];
            acc[mt][0] = __builtin_amdgcn_mfma_f32_16x16x32_bf16(a, b0, acc[mt][0], 0, 0, 0);
            acc[mt][1] = __builtin_amdgcn_mfma_f32_16x16x32_bf16(a, b1, acc[mt][1], 0, 0, 0);
        }
    }

#pragma unroll
    for (int mt = 0; mt < 4; ++mt) {
#pragma unroll
        for (int nt = 0; nt < 2; ++nt) {
            int col = wave * 32 + nt * 16 + m;
            int sup = col >> 6, ch = col & 63;
#pragma unroll
            for (int r = 0; r < 4; ++r) {
                int row = row0 + mt * 16 + q * 4 + r;
                if (row < N_NODES)
                    psb[((size_t)sup * N_NODES + row) * OUT_DIM + ch] =
                        f2bf(acc[mt][nt][r]);
            }
        }
    }
}

// ---------------------------------------------------------------------------
// Bin (unchanged R1): route edges into fixed-capacity 256-node bucket staging
// regions. rec = (val:32 | srcsup:18 | dst_lo:8).
// ---------------------------------------------------------------------------
__global__ __launch_bounds__(256) void bin_kernel(
    const int* __restrict__ edge_src, const int* __restrict__ edge_dst,
    const float* __restrict__ edge_val,
    int* __restrict__ bcur, u64* __restrict__ sbuf)
{
    __shared__ int hist[NBUCK], gbase[NBUCK], cnt[NBUCK];
    const int base = blockIdx.x * CHUNK + threadIdx.x;

    u64 pk[16];
    int bk[16];
    for (int i = threadIdx.x; i < NBUCK; i += 256) hist[i] = 0;
    __syncthreads();

#pragma unroll
    for (int j = 0; j < 16; ++j) {
        int gid = base + j * 256;
        bk[j] = -1;
        if (gid < N_TOT_EDGES) {
            int dst = edge_dst[gid];
            int src = edge_src[gid];
            float val = edge_val[gid];
            int srcsup = (gid >= N_EDGES ? N_NODES : 0) + src;
            bk[j] = dst >> SHIFT;
            pk[j] = ((u64)__float_as_uint(val) << 32)
                  | (u64)(((unsigned)srcsup << SHIFT) | (unsigned)(dst & (BUCKN - 1)));
            atomicAdd(&hist[bk[j]], 1);
        }
    }
    __syncthreads();
    for (int i = threadIdx.x; i < NBUCK; i += 256) {
        int h = hist[i];
        gbase[i] = h ? atomicAdd(&bcur[i], h) : 0;
        cnt[i] = 0;
    }
    __syncthreads();
#pragma unroll
    for (int j = 0; j < 16; ++j) {
        if (bk[j] >= 0) {
            int loc = atomicAdd(&cnt[bk[j]], 1);
            size_t pos = (size_t)gbase[bk[j]] + loc;
            if (pos < (size_t)(bk[j] + 1) * CAP)   // safety clamp only
                sbuf[pos] = pk[j];
        }
    }
}

// ---------------------------------------------------------------------------
// Fused scatter-accumulate: one block per 256-node bucket, acc[256][64] fp32
// in 64 KB LDS. Only change vs R1: native ds_add_f32 instead of the CAS-loop
// that HIP's float atomicAdd emits for LDS, + explicit lgkmcnt drain before
// the flush barrier (inline-asm DS ops are invisible to the compiler's
// waitcnt model).
// ---------------------------------------------------------------------------
__global__ __launch_bounds__(1024) void scatter_kernel(
    const ushort* __restrict__ psb, const u64* __restrict__ sbuf,
    const int* __restrict__ bcur, float* __restrict__ out)
{
    __shared__ float acc[BUCKN * OUT_DIM];          // 65536 B
    const int b = blockIdx.x;

    float4* a4 = (float4*)acc;
    for (int i = threadIdx.x; i < BUCKN * OUT_DIM / 4; i += 1024)
        a4[i] = (float4){0.f, 0.f, 0.f, 0.f};
    __syncthreads();

    int cnt = bcur[b] - b * CAP;
    if (cnt > CAP) cnt = CAP;
    const int2* sb = (const int2*)(sbuf + (size_t)b * CAP);
    const int wave = threadIdx.x >> 6;
    const int lane = threadIdx.x & 63;

    for (int base = wave << 6; base < cnt; base += 16 * 64) {
        const int n = min(64, cnt - base);
        int2 r = make_int2(0, 0);
        if (lane < n) r = sb[base + lane];
        int j = 0;
        for (; j + 8 <= n; j += 8) {
            int a0 = __builtin_amdgcn_readlane(r.x, j + 0);
            int a1 = __builtin_amdgcn_readlane(r.x, j + 1);
            int a2 = __builtin_amdgcn_readlane(r.x, j + 2);
            int a3 = __builtin_amdgcn_readlane(r.x, j + 3);
            int a4i = __builtin_amdgcn_readlane(r.x, j + 4);
            int a5 = __builtin_amdgcn_readlane(r.x, j + 5);
            int a6 = __builtin_amdgcn_readlane(r.x, j + 6);
            int a7 = __builtin_amdgcn_readlane(r.x, j + 7);
            float v0 = __int_as_float(__builtin_amdgcn_readlane(r.y, j + 0));
            float v1 = __int_as_float(__builtin_amdgcn_readlane(r.y, j + 1));
            float v2 = __int_as_float(__builtin_amdgcn_readlane(r.y, j + 2));
            float v3 = __int_as_float(__builtin_amdgcn_readlane(r.y, j + 3));
            float v4 = __int_as_float(__builtin_amdgcn_readlane(r.y, j + 4));
            float v5 = __int_as_float(__builtin_amdgcn_readlane(r.y, j + 5));
            float v6 = __int_as_float(__builtin_amdgcn_readlane(r.y, j + 6));
            float v7 = __int_as_float(__builtin_amdgcn_readlane(r.y, j + 7));
            float p0 = bf2f(psb[(size_t)((unsigned)a0 >> SHIFT) * OUT_DIM + lane]);
            float p1 = bf2f(psb[(size_t)((unsigned)a1 >> SHIFT) * OUT_DIM + lane]);
            float p2 = bf2f(psb[(size_t)((unsigned)a2 >> SHIFT) * OUT_DIM + lane]);
            float p3 = bf2f(psb[(size_t)((unsigned)a3 >> SHIFT) * OUT_DIM + lane]);
            float p4 = bf2f(psb[(size_t)((unsigned)a4i >> SHIFT) * OUT_DIM + lane]);
            float p5 = bf2f(psb[(size_t)((unsigned)a5 >> SHIFT) * OUT_DIM + lane]);
            float p6 = bf2f(psb[(size_t)((unsigned)a6 >> SHIFT) * OUT_DIM + lane]);
            float p7 = bf2f(psb[(size_t)((unsigned)a7 >> SHIFT) * OUT_DIM + lane]);
            lds_fadd(&acc[((a0 & (BUCKN - 1)) << 6) + lane], p0 * v0);
            lds_fadd(&acc[((a1 & (BUCKN - 1)) << 6) + lane], p1 * v1);
            lds_fadd(&acc[((a2 & (BUCKN - 1)) << 6) + lane], p2 * v2);
            lds_fadd(&acc[((a3 & (BUCKN - 1)) << 6) + lane], p3 * v3);
            lds_fadd(&acc[((a4i & (BUCKN - 1)) << 6) + lane], p4 * v4);
            lds_fadd(&acc[((a5 & (BUCKN - 1)) << 6) + lane], p5 * v5);
            lds_fadd(&acc[((a6 & (BUCKN - 1)) << 6) + lane], p6 * v6);
            lds_fadd(&acc[((a7 & (BUCKN - 1)) << 6) + lane], p7 * v7);
        }
        for (; j < n; ++j) {
            int   a = __builtin_amdgcn_readlane(r.x, j);
            float v = __int_as_float(__builtin_amdgcn_readlane(r.y, j));
            float p = bf2f(psb[(size_t)((unsigned)a >> SHIFT) * OUT_DIM + lane]);
            lds_fadd(&acc[((a & (BUCKN - 1)) << 6) + lane], p * v);
        }
    }
    // Drain inline-asm DS ops before the barrier (compiler can't see them).
    asm volatile("s_waitcnt lgkmcnt(0)" ::: "memory");
    __syncthreads();

    // flush: fused ReLU, fully coalesced float4 stores
    const int nbase = b << SHIFT;
    for (int i = threadIdx.x; i < BUCKN * OUT_DIM / 4; i += 1024) {
        int row = i >> 4;                           // 16 float4 per row
        if (nbase + row < N_NODES) {
            float4 v = a4[i];
            v.x = fmaxf(v.x, 0.f); v.y = fmaxf(v.y, 0.f);
            v.z = fmaxf(v.z, 0.f); v.w = fmaxf(v.w, 0.f);
            ((float4*)out)[(size_t)(nbase + row) * 16 + (i & 15)] = v;
        }
    }
}

extern "C" void kernel_launch(void* const* d_in, const int* in_sizes, int n_in,
                              void* d_out, int out_size, void* d_ws, size_t ws_size,
                              hipStream_t stream)
{
    const float* x        = (const float*)d_in[0];
    const float* W        = (const float*)d_in[1];
    const float* edge_val = (const float*)d_in[2];
    const int*   edge_src = (const int*)d_in[3];
    const int*   edge_dst = (const int*)d_in[4];
    float* out = (float*)d_out;

    // workspace layout (total 54,494,752 B, well under proven 77.67 MB):
    //   psb  [2*100000*64 bf16]   @ 0           (25,600,000)
    //   sbuf [391*9216 u64]       @ 25,600,000  (28,827,648)  fixed-cap staging
    //   bcur [391 int]            @ 54,427,648  (1,564)
    //   Wb   [32768 ushort]       @ 54,429,216  (65,536)  16B-aligned
    ushort* psb = (ushort*)d_ws;
    char* p = (char*)d_ws;
    u64*  sbuf = (u64*)(p + 25600000);
    int*  bcur = (int*)(p + 54427648);
    ushort* Wb = (ushort*)(p + 54429216);

    wb_kernel<<<128, 256, 0, stream>>>(W, Wb, bcur);
    gemm_kernel<<<NBLK, 256, 0, stream>>>(x, Wb, psb);
    bin_kernel<<<BGRID, 256, 0, stream>>>(edge_src, edge_dst, edge_val,
                                          bcur, sbuf);
    scatter_kernel<<<NBUCK, 1024, 0, stream>>>(psb, sbuf, bcur, out);
}

// Round 3
// 369.624 us; speedup vs baseline: 4.3015x; 4.3015x over previous
//
#include <hip/hip_runtime.h>

#define N_NODES 100000
#define N_EDGES 1600000
#define N_SUP 2
#define IN_DIM 256
#define OUT_DIM 64
#define N_TOT_EDGES (N_SUP * N_EDGES)   // 3,200,000
#define GM 64                           // GEMM M-tile per block
#define NBLK ((N_NODES + GM - 1) / GM)  // 1563

#define SHIFT 8                         // 256 nodes per bucket
#define BUCKN 256
#define NBUCK ((N_NODES + BUCKN - 1) / BUCKN)      // 391
#define CAP 9216                        // bucket staging cap: mean 8192, +11 sigma
#define CHUNK 4096                      // edges per bin block
#define BGRID ((N_TOT_EDGES + CHUNK - 1) / CHUNK)  // 782

typedef __attribute__((ext_vector_type(8))) short short8;   // 8 bf16
typedef __attribute__((ext_vector_type(4))) float floatx4;  // MFMA acc
typedef unsigned long long u64;

__device__ inline ushort f2bf(float f) {          // fp32 -> bf16 RNE
    unsigned u = __float_as_uint(f);
    return (ushort)((u + 0x7fffu + ((u >> 16) & 1u)) >> 16);
}
__device__ inline float bf2f(ushort h) {
    return __uint_as_float(((unsigned)h) << 16);
}

// ---------------------------------------------------------------------------
// W pre-swizzle into mfma_f32_16x16x32_bf16 B-fragment order (proven) +
// bucket-cursor init folded in.
// ---------------------------------------------------------------------------
__global__ __launch_bounds__(256) void wb_kernel(
    const float* __restrict__ W, ushort* __restrict__ Wb,
    int* __restrict__ bcur)
{
    int idx = blockIdx.x * 256 + threadIdx.x;      // 0..32767
    if (idx < NBUCK) bcur[idx] = idx * CAP;
    int j    = idx & 7;
    int lane = (idx >> 3) & 63;
    int nt   = (idx >> 9) & 7;
    int ks   = idx >> 12;
    int k = ks * 32 + (lane >> 4) * 8 + j;
    int n = nt * 16 + (lane & 15);
    Wb[idx] = f2bf(W[((size_t)(n >> 6) * IN_DIM + k) * OUT_DIM + (n & 63)]);
}

// ---------------------------------------------------------------------------
// MFMA GEMM (proven): psb[sup][node][64] bf16 = x @ W[sup]
// ---------------------------------------------------------------------------
__global__ __launch_bounds__(256) void gemm_kernel(
    const float* __restrict__ x, const ushort* __restrict__ Wb,
    ushort* __restrict__ psb)
{
    __shared__ __align__(16) ushort xs[GM][264];
    const int row0 = blockIdx.x * GM;
    const int trow = threadIdx.x >> 6;
    const int tcol = threadIdx.x & 63;

#pragma unroll
    for (int j = 0; j < 16; ++j) {
        int r = j * 4 + trow;
        int gr = row0 + r;
        if (gr > N_NODES - 1) gr = N_NODES - 1;
        float4 v = ((const float4*)x)[(size_t)gr * 64 + tcol];
        ushort4 h;
        h.x = f2bf(v.x); h.y = f2bf(v.y); h.z = f2bf(v.z); h.w = f2bf(v.w);
        *(ushort4*)&xs[r][tcol * 4] = h;
    }
    __syncthreads();

    const int wave = threadIdx.x >> 6;
    const int lane = threadIdx.x & 63;
    const int q = lane >> 4;
    const int m = lane & 15;
    const int nt0 = wave * 2;

    floatx4 acc[4][2];
#pragma unroll
    for (int mt = 0; mt < 4; ++mt)
#pragma unroll
        for (int nt = 0; nt < 2; ++nt)
            acc[mt][nt] = (floatx4){0.f, 0.f, 0.f, 0.f};

    const short8* Wbv = (const short8*)Wb;
#pragma unroll
    for (int ks = 0; ks < 8; ++ks) {
        short8 b0 = Wbv[((ks * 8) + nt0) * 64 + lane];
        short8 b1 = Wbv[((ks * 8) + nt0 + 1) * 64 + lane];
#pragma unroll
        for (int mt = 0; mt < 4; ++mt) {
            short8 a = *(const short8*)&xs[mt * 16 + m][ks * 32 + q * 8];
            acc[mt][0] = __builtin_amdgcn_mfma_f32_16x16x32_bf16(a, b0, acc[mt][0], 0, 0, 0);
            acc[mt][1] = __builtin_amdgcn_mfma_f32_16x16x32_bf16(a, b1, acc[mt][1], 0, 0, 0);
        }
    }

#pragma unroll
    for (int mt = 0; mt < 4; ++mt) {
#pragma unroll
        for (int nt = 0; nt < 2; ++nt) {
            int col = wave * 32 + nt * 16 + m;
            int sup = col >> 6, ch = col & 63;
#pragma unroll
            for (int r = 0; r < 4; ++r) {
                int row = row0 + mt * 16 + q * 4 + r;
                if (row < N_NODES)
                    psb[((size_t)sup * N_NODES + row) * OUT_DIM + ch] =
                        f2bf(acc[mt][nt][r]);
            }
        }
    }
}

// ---------------------------------------------------------------------------
// Bin (proven in R1/R2): route edges into fixed-capacity 256-node bucket
// staging regions. rec = (val:32 | srcsup:18 | dst_lo:8).
// ---------------------------------------------------------------------------
__global__ __launch_bounds__(256) void bin_kernel(
    const int* __restrict__ edge_src, const int* __restrict__ edge_dst,
    const float* __restrict__ edge_val,
    int* __restrict__ bcur, u64* __restrict__ sbuf)
{
    __shared__ int hist[NBUCK], gbase[NBUCK], cnt[NBUCK];
    const int base = blockIdx.x * CHUNK + threadIdx.x;

    u64 pk[16];
    int bk[16];
    for (int i = threadIdx.x; i < NBUCK; i += 256) hist[i] = 0;
    __syncthreads();

#pragma unroll
    for (int j = 0; j < 16; ++j) {
        int gid = base + j * 256;
        bk[j] = -1;
        if (gid < N_TOT_EDGES) {
            int dst = edge_dst[gid];
            int src = edge_src[gid];
            float val = edge_val[gid];
            int srcsup = (gid >= N_EDGES ? N_NODES : 0) + src;
            bk[j] = dst >> SHIFT;
            pk[j] = ((u64)__float_as_uint(val) << 32)
                  | (u64)(((unsigned)srcsup << SHIFT) | (unsigned)(dst & (BUCKN - 1)));
            atomicAdd(&hist[bk[j]], 1);
        }
    }
    __syncthreads();
    for (int i = threadIdx.x; i < NBUCK; i += 256) {
        int h = hist[i];
        gbase[i] = h ? atomicAdd(&bcur[i], h) : 0;
        cnt[i] = 0;
    }
    __syncthreads();
#pragma unroll
    for (int j = 0; j < 16; ++j) {
        if (bk[j] >= 0) {
            int loc = atomicAdd(&cnt[bk[j]], 1);
            size_t pos = (size_t)gbase[bk[j]] + loc;
            if (pos < (size_t)(bk[j] + 1) * CAP)   // safety clamp only
                sbuf[pos] = pk[j];
        }
    }
}

// ---------------------------------------------------------------------------
// Fused group+gather: one 1024-thr block per 256-node bucket.
//   sort phase: int-atomic hist (proven R0 pattern) -> LDS scan ->
//               int-atomic cursors -> counting-sort records into 72 KB LDS.
//   gather phase: R0's PROVEN inner loop (cooperative record fetch, __shfl
//               broadcast, 4-deep psb-load ILP, register FMA, fused ReLU),
//               sourcing records from LDS. NO fp atomics anywhere.
// Replaces bhist+bscan+group+gather and the erec/start global round-trip.
// ---------------------------------------------------------------------------
__global__ __launch_bounds__(1024) void fused_kernel(
    const ushort* __restrict__ psb, const u64* __restrict__ sbuf,
    const int* __restrict__ bcur, float* __restrict__ out)
{
    __shared__ u64 srec[CAP];                      // 73,728 B
    __shared__ int h[BUCKN], sc[BUCKN], cur[BUCKN];  // 3 KB -> 76.8 KB total
    const int b = blockIdx.x;
    const int tid = threadIdx.x;

    int cnt = bcur[b] - b * CAP;
    if (cnt > CAP) cnt = CAP;
    const u64* sb = sbuf + (size_t)b * CAP;

    if (tid < BUCKN) h[tid] = 0;
    __syncthreads();

    // pass 1: histogram of local node ids (coalesced global read #1)
    for (int i = tid; i < cnt; i += 1024)
        atomicAdd(&h[(int)(sb[i] & (BUCKN - 1))], 1);
    __syncthreads();

    // inclusive Hillis-Steele scan over 256 counts (first 256 threads)
    if (tid < BUCKN) sc[tid] = h[tid];
    __syncthreads();
    for (int off = 1; off < BUCKN; off <<= 1) {
        int add = (tid < BUCKN && tid >= off) ? sc[tid - off] : 0;
        __syncthreads();
        if (tid < BUCKN) sc[tid] += add;
        __syncthreads();
    }
    if (tid < BUCKN) cur[tid] = sc[tid] - h[tid];   // exclusive base
    __syncthreads();

    // pass 2: counting-sort into LDS (global read #2 is L2-hot: 72 KB window)
    for (int i = tid; i < cnt; i += 1024) {
        u64 r = sb[i];
        int pos = atomicAdd(&cur[(int)(r & (BUCKN - 1))], 1);
        srec[pos] = r;
    }
    __syncthreads();

    // gather phase: wave w owns local nodes w*16 .. w*16+15
    const int wave = tid >> 6;
    const int lane = tid & 63;
    const int nbase = b << SHIFT;

    for (int t = 0; t < 16; ++t) {
        const int d = wave * 16 + t;
        const int e = sc[d];                       // uniform LDS reads
        const int s = e - h[d];
        float acc = 0.f;
        for (int base = s; base < e; base += 64) {
            const int n = min(64, e - base);
            u64 rr = 0;
            if (lane < n) rr = srec[base + lane];
            int rx = (int)(unsigned)rr;            // srcsup<<8 | dst_lo
            int ry = (int)(rr >> 32);              // val bits
            int j = 0;
            for (; j + 4 <= n; j += 4) {
                int   r0 = __shfl(rx, j),     r1 = __shfl(rx, j + 1);
                int   r2 = __shfl(rx, j + 2), r3 = __shfl(rx, j + 3);
                float v0 = __int_as_float(__shfl(ry, j));
                float v1 = __int_as_float(__shfl(ry, j + 1));
                float v2 = __int_as_float(__shfl(ry, j + 2));
                float v3 = __int_as_float(__shfl(ry, j + 3));
                float p0 = bf2f(psb[(size_t)((unsigned)r0 >> SHIFT) * OUT_DIM + lane]);
                float p1 = bf2f(psb[(size_t)((unsigned)r1 >> SHIFT) * OUT_DIM + lane]);
                float p2 = bf2f(psb[(size_t)((unsigned)r2 >> SHIFT) * OUT_DIM + lane]);
                float p3 = bf2f(psb[(size_t)((unsigned)r3 >> SHIFT) * OUT_DIM + lane]);
                acc = fmaf(p0, v0, acc);
                acc = fmaf(p1, v1, acc);
                acc = fmaf(p2, v2, acc);
                acc = fmaf(p3, v3, acc);
            }
            for (; j < n; ++j) {
                int   r0 = __shfl(rx, j);
                float v0 = __int_as_float(__shfl(ry, j));
                acc = fmaf(bf2f(psb[(size_t)((unsigned)r0 >> SHIFT) * OUT_DIM + lane]),
                           v0, acc);
            }
        }
        const int n = nbase + d;
        if (n < N_NODES)
            out[(size_t)n * OUT_DIM + lane] = fmaxf(acc, 0.f);
    }
}

extern "C" void kernel_launch(void* const* d_in, const int* in_sizes, int n_in,
                              void* d_out, int out_size, void* d_ws, size_t ws_size,
                              hipStream_t stream)
{
    const float* x        = (const float*)d_in[0];
    const float* W        = (const float*)d_in[1];
    const float* edge_val = (const float*)d_in[2];
    const int*   edge_src = (const int*)d_in[3];
    const int*   edge_dst = (const int*)d_in[4];
    float* out = (float*)d_out;

    // workspace layout (total 54,494,752 B, well under proven 77.67 MB):
    //   psb  [2*100000*64 bf16]   @ 0           (25,600,000)
    //   sbuf [391*9216 u64]       @ 25,600,000  (28,827,648)  fixed-cap staging
    //   bcur [391 int]            @ 54,427,648  (1,564)
    //   Wb   [32768 ushort]       @ 54,429,216  (65,536)  16B-aligned
    ushort* psb = (ushort*)d_ws;
    char* p = (char*)d_ws;
    u64*  sbuf = (u64*)(p + 25600000);
    int*  bcur = (int*)(p + 54427648);
    ushort* Wb = (ushort*)(p + 54429216);

    wb_kernel<<<128, 256, 0, stream>>>(W, Wb, bcur);
    gemm_kernel<<<NBLK, 256, 0, stream>>>(x, Wb, psb);
    bin_kernel<<<BGRID, 256, 0, stream>>>(edge_src, edge_dst, edge_val,
                                          bcur, sbuf);
    fused_kernel<<<NBUCK, 1024, 0, stream>>>(psb, sbuf, bcur, out);
}